// Round 1
// baseline (88.965 us; speedup 1.0000x reference)
//
#include <hip/hip_runtime.h>
#include <stdint.h>

// ---------------------------------------------------------------------------
// quantized_conv: bit-serial IMC conv simulation, exact integer path via i8 MFMA
//
// out[b,o,p] = (norm/255) * sum_{c,s,t} 4^(s+t) *
//    ( min(31, sum_f a_s[f]*wp_t[f]) - min(31, sum_f a_s[f]*wn_t[f]) )
//
// R3 restructure: weight quantization + 2-bit digit-plane expansion moved out
// of k_main into 4 extra blocks of k_prep (each redundantly computes the
// global |w| max, then expands 1/4 of the weights into Bq[sign][t][oc][640]
// bytes = 320 KB, L2-hot). k_main is now pure global->MFMA->fold: no LDS,
// no barriers, no per-block quant (was 64x redundant at 1 wave/SIMD).
// ---------------------------------------------------------------------------

typedef int v4i __attribute__((ext_vector_type(4)));
typedef unsigned int v4u __attribute__((ext_vector_type(4)));

// workspace layout (bytes)
#define WS_NORM   0          // 1 float: |w| max (norm)
#define WS_B      1024       // 8*64*640 = 327680 bytes: digit planes [sg*4+t][oc][kpos]
#define WS_AQ     331776     // 4096*640 bytes: unfolded patch bytes [m][k], k=c*128+j
#define B_PLANE   40960      // 64*640 bytes per plane

__device__ __forceinline__ unsigned char quant_in(float x) {
  x = fminf(fmaxf(x, -8.0f), 7.9375f);     // fixed-point clip (int_bits=3, frac=4)
  int q = (int)rintf(x * 16.0f);           // round-half-even == jnp.round
  return (unsigned char)(q & 255);         // two's complement byte
}

// ---------------------------------------------------------------------------
// k_prep: im2col byte unfold (quantize floats on the fly) + weight digit planes
// grid: 2560 unfold blocks + 4 weight blocks, 256 thr
// ---------------------------------------------------------------------------
__global__ __launch_bounds__(256) void k_prep(
    const float* __restrict__ in, const float* __restrict__ w,
    unsigned char* __restrict__ Aq, unsigned char* __restrict__ Bq,
    float* __restrict__ nrm, float* __restrict__ out_scalar)
{
  __shared__ float smax[4];
  int bid = blockIdx.x, tid = threadIdx.x;
  if (bid < 2560) {
    if (bid == 0 && tid == 0) out_scalar[0] = 0.0f;   // second tuple output
    unsigned int widx = bid * 256 + tid;            // dword index: m*160 + kw
    unsigned int m  = ((widx >> 5) * 52429u) >> 18; // widx/160
    unsigned int kw = widx - m * 160;
    int b = m >> 10, p = m & 1023;
    int y = p >> 5, x = p & 31;
    unsigned int pack = 0;
    #pragma unroll
    for (int i = 0; i < 4; ++i) {
      unsigned int k = kw * 4 + i;
      unsigned int c = k >> 7;
      unsigned int j = k & 127;
      unsigned int csize = (c == 4) ? 112 : 116;
      unsigned int bv = 0;
      if (j < csize) {
        unsigned int f  = c * 116 + j;              // f = ic*9 + dy*3 + dx
        unsigned int ic = (f * 7282u) >> 16;        // f/9  (f<576)
        unsigned int r9 = f - ic * 9;
        unsigned int dy = (r9 * 11u) >> 5;          // r9/3
        unsigned int dx = r9 - dy * 3;
        int iy = y + (int)dy - 1, ix = x + (int)dx - 1;
        if (iy >= 0 && iy < 32 && ix >= 0 && ix < 32)
          bv = quant_in(in[((b * 64 + ic) * 32 + iy) * 32 + ix]);
      }
      pack |= bv << (8 * i);
    }
    ((unsigned int*)Aq)[widx] = pack;
  } else {
    // ---- weight pipeline: 4 blocks, each re-computes global max (cheap,
    // deterministic) then expands 1/4 of the weights into digit planes ----
    int q = bid - 2560;                             // 0..3
    float a = 0.0f;
    #pragma unroll 4
    for (int i = 0; i < 36; ++i) {                  // 9216 float4 = all weights
      float4 v = ((const float4*)w)[i * 256 + tid];
      a = fmaxf(a, fmaxf(fmaxf(fabsf(v.x), fabsf(v.y)),
                         fmaxf(fabsf(v.z), fabsf(v.w))));
    }
    #pragma unroll
    for (int off = 32; off > 0; off >>= 1)
      a = fmaxf(a, __shfl_down(a, off, 64));
    if ((tid & 63) == 0) smax[tid >> 6] = a;
    __syncthreads();
    float norm = fmaxf(fmaxf(smax[0], smax[1]), fmaxf(smax[2], smax[3]));
    norm = (norm > 0.0f) ? norm : 1.0f;
    if (q == 0 && tid == 0) nrm[0] = norm;
    float sc = 255.0f / norm;

    unsigned int* Bd = (unsigned int*)Bq;
    // phase 2: quantize + digit-plane expand. 4-aligned f-groups never straddle
    // a 116-chunk boundary (116 % 4 == 0), so each group is one plane dword.
    for (int g = 0; g < 9; ++g) {
      int grp = g * 1024 + q * 256 + tid;           // [0, 9216) float4 groups
      unsigned int m4 = (unsigned)grp >> 4;         // = oc*9 + (fg>>4), <576
      unsigned int oc = (m4 * 7282u) >> 16;         // /9
      unsigned int fg = (unsigned)grp - oc * 144;   // f4-group within oc
      unsigned int f  = fg * 4;
      unsigned int c  = (f * 565u) >> 16;           // f/116 (f<576)
      unsigned int j  = f - c * 116;
      unsigned int col = c * 32 + (j >> 2);         // dword col in 640-byte row
      float4 wv = ((const float4*)w)[grp];
      int p0 = (int)rintf(fmaxf(wv.x, 0.0f) * sc);
      int p1 = (int)rintf(fmaxf(wv.y, 0.0f) * sc);
      int p2 = (int)rintf(fmaxf(wv.z, 0.0f) * sc);
      int p3 = (int)rintf(fmaxf(wv.w, 0.0f) * sc);
      int n0 = (int)rintf(fmaxf(-wv.x, 0.0f) * sc);
      int n1 = (int)rintf(fmaxf(-wv.y, 0.0f) * sc);
      int n2 = (int)rintf(fmaxf(-wv.z, 0.0f) * sc);
      int n3 = (int)rintf(fmaxf(-wv.w, 0.0f) * sc);
      unsigned int Pp = (unsigned)p0 | ((unsigned)p1 << 8) |
                        ((unsigned)p2 << 16) | ((unsigned)p3 << 24);
      unsigned int Pn = (unsigned)n0 | ((unsigned)n1 << 8) |
                        ((unsigned)n2 << 16) | ((unsigned)n3 << 24);
      #pragma unroll
      for (int t = 0; t < 4; ++t) {
        Bd[((t)     * 64 + oc) * 160 + col] = (Pp >> (2 * t)) & 0x03030303u;
        Bd[((4 + t) * 64 + oc) * 160 + col] = (Pn >> (2 * t)) & 0x03030303u;
      }
    }
    // phase 3: zero the chunk-pad dwords (workspace is poisoned each iter).
    // per (plane,oc): chunks 0-3 pad dwords {29,30,31}, chunk 4 pads {28..31}
    int gtid = q * 256 + tid;                       // [0,1024), 8 pads each
    #pragma unroll
    for (int e = 0; e < 8; ++e) {
      int idx = gtid * 8 + e;                       // [0, 8192)
      int plane = idx >> 10;
      int r = idx & 1023;
      int oc = r >> 4;
      int s = r & 15;
      int c, d;
      if (s < 12) { c = (s * 11) >> 5; d = 29 + s - 3 * c; }
      else        { c = 4;             d = s + 16; }
      Bd[(plane * 64 + oc) * 160 + c * 32 + d] = 0u;
    }
  }
}

// extract 2-bit field s of each byte in a packed dword vector
__device__ __forceinline__ v4i bits2(v4u w, int s) {
  v4u r = (w >> (unsigned)(2 * s)) & 0x03030303u;
  return (v4i)r;
}

// ---------------------------------------------------------------------------
// k_main: pure MFMA/clip/fold. No LDS, no barriers.
// grid: 256 blocks (64 mtiles x 4 otiles), 256 thr = 4 waves (16m x 16o each)
// ---------------------------------------------------------------------------
__global__ __launch_bounds__(256) void k_main(
    const unsigned char* __restrict__ Aq, const unsigned char* __restrict__ Bq,
    const float* __restrict__ nrm, float* __restrict__ out)
{
  int tid   = threadIdx.x;
  int lane  = tid & 63;
  int wave  = tid >> 6;
  int mtile = blockIdx.x >> 2;
  int otile = blockIdx.x & 3;

  int r16  = lane & 15;
  int kgrp = lane >> 4;                 // A: m=lane&15,k=kgrp*16+j ; B: n=lane&15
  int m = mtile * 64 + wave * 16 + r16;
  const unsigned char* ap = Aq + m * 640 + kgrp * 16;
  const unsigned char* bp = Bq + (otile * 16 + r16) * 640 + kgrp * 16;
  float fsc = nrm[0] / 255.0f;

  v4i outacc = {0, 0, 0, 0};

  #pragma unroll
  for (int c = 0; c < 5; ++c) {
    v4u a0 = *(const v4u*)(ap + c * 128);
    v4u a1 = *(const v4u*)(ap + c * 128 + 64);
    v4i b0[8], b1[8];                   // [plane]: 0..3 pos t, 4..7 neg t
    #pragma unroll
    for (int pl = 0; pl < 8; ++pl) {
      b0[pl] = *(const v4i*)(bp + pl * B_PLANE + c * 128);
      b1[pl] = *(const v4i*)(bp + pl * B_PLANE + c * 128 + 64);
    }

    #pragma unroll
    for (int s = 0; s < 4; ++s) {
      v4i as0 = bits2(a0, s), as1 = bits2(a1, s);
      #pragma unroll
      for (int t = 0; t < 4; ++t) {
        v4i z = {0, 0, 0, 0};
        v4i pacc = __builtin_amdgcn_mfma_i32_16x16x64_i8(as0, b0[t], z, 0, 0, 0);
        pacc     = __builtin_amdgcn_mfma_i32_16x16x64_i8(as1, b1[t], pacc, 0, 0, 0);
        v4i nacc = __builtin_amdgcn_mfma_i32_16x16x64_i8(as0, b0[4 + t], z, 0, 0, 0);
        nacc     = __builtin_amdgcn_mfma_i32_16x16x64_i8(as1, b1[4 + t], nacc, 0, 0, 0);
        int sh = 2 * (s + t);
        #pragma unroll
        for (int r = 0; r < 4; ++r) {
          int d = (pacc[r] < 31 ? pacc[r] : 31) - (nacc[r] < 31 ? nacc[r] : 31);
          outacc[r] += d << sh;   // |outacc| <= 31*85*85*5 ~ 1.12e6, exact
        }
      }
    }
  }

  // C/D layout: col(n=o) = lane&15, row(m) = (lane>>4)*4 + r
  int oc = otile * 16 + r16;
  #pragma unroll
  for (int r = 0; r < 4; ++r) {
    int mo = mtile * 64 + wave * 16 + kgrp * 4 + r;
    int b = mo >> 10, p = mo & 1023;
    out[(b * 64 + oc) * 1024 + p] = (float)outacc[r] * fsc;
  }
}

extern "C" void kernel_launch(void* const* d_in, const int* in_sizes, int n_in,
                              void* d_out, int out_size, void* d_ws, size_t ws_size,
                              hipStream_t stream) {
  const float* inp = (const float*)d_in[0];   // (4,64,32,32) f32
  const float* wgt = (const float*)d_in[1];   // (64,64,3,3)  f32
  float* out = (float*)d_out;                 // 262144 + 1 f32
  unsigned char* ws = (unsigned char*)d_ws;

  float*         nrm = (float*)(ws + WS_NORM);
  unsigned char* Bq  = ws + WS_B;
  unsigned char* Aq  = ws + WS_AQ;

  k_prep<<<2564, 256, 0, stream>>>(inp, wgt, Aq, Bq, nrm, out + 262144);
  k_main<<<256, 256, 0, stream>>>(Aq, Bq, nrm, out);
}

// Round 2
// 82.152 us; speedup vs baseline: 1.0829x; 1.0829x over previous
//
#include <hip/hip_runtime.h>
#include <stdint.h>

// ---------------------------------------------------------------------------
// quantized_conv: bit-serial IMC conv simulation, exact integer path via i8 MFMA
//
// out[b,o,p] = (norm/255) * sum_{c,s,t} 4^(s+t) *
//    ( min(31, sum_f a_s[f]*wp_t[f]) - min(31, sum_f a_s[f]*wn_t[f]) )
//
// R4: hybrid of R2/R3 structures.
//  - k_prep: 2560 unfold blocks (unchanged) + 9 weight blocks that compute the
//    global |w| max (redundantly, order-insensitive fmax) and emit the PACKED
//    pos/neg byte matrix Bqb[otile][sign][16][640] (81920 B), XOR-swizzled
//    (byte ^= (row&7)<<4) at the source, chunk-pads zeroed (ws is poisoned).
//  - k_main: stages its otile's 20 KB slice into LDS with 5 coalesced 16B
//    copies, then the proven bits2+MFMA loop. No quant, no LDS zeroing, no
//    norm reduce, no bank conflicts (swizzled reads hit the 8-lane/bank-group
//    b128 floor). Digit extraction stays in VALU (cheaper than 8x plane loads,
//    which was R3's k_main regression).
// ---------------------------------------------------------------------------

typedef int v4i __attribute__((ext_vector_type(4)));
typedef unsigned int v4u __attribute__((ext_vector_type(4)));

// workspace layout (bytes)
#define WS_NORM   0          // 1 float: |w| max (norm)
#define WS_B      1024       // 4*2*16*640 = 81920 B packed byte slices (swizzled)
#define WS_AQ     131072     // 4096*640 bytes: unfolded patch bytes [m][k], k=c*128+j
#define B_SLICE   20480      // bytes per otile slice
#define B_SG      10240      // bytes per sign within a slice

__device__ __forceinline__ unsigned char quant_in(float x) {
  x = fminf(fmaxf(x, -8.0f), 7.9375f);     // fixed-point clip (int_bits=3, frac=4)
  int q = (int)rintf(x * 16.0f);           // round-half-even == jnp.round
  return (unsigned char)(q & 255);         // two's complement byte
}

// ---------------------------------------------------------------------------
// k_prep: im2col byte unfold (quantize floats on the fly) + weight byte matrix
// grid: 2560 unfold blocks + 9 weight blocks, 256 thr
// ---------------------------------------------------------------------------
__global__ __launch_bounds__(256) void k_prep(
    const float* __restrict__ in, const float* __restrict__ w,
    unsigned char* __restrict__ Aq, unsigned char* __restrict__ Bqb,
    float* __restrict__ nrm, float* __restrict__ out_scalar)
{
  __shared__ float smax[4];
  int bid = blockIdx.x, tid = threadIdx.x;
  if (bid < 2560) {
    if (bid == 0 && tid == 0) out_scalar[0] = 0.0f;   // second tuple output
    unsigned int widx = bid * 256 + tid;            // dword index: m*160 + kw
    unsigned int m  = ((widx >> 5) * 52429u) >> 18; // widx/160
    unsigned int kw = widx - m * 160;
    int b = m >> 10, p = m & 1023;
    int y = p >> 5, x = p & 31;
    unsigned int pack = 0;
    #pragma unroll
    for (int i = 0; i < 4; ++i) {
      unsigned int k = kw * 4 + i;
      unsigned int c = k >> 7;
      unsigned int j = k & 127;
      unsigned int csize = (c == 4) ? 112 : 116;
      unsigned int bv = 0;
      if (j < csize) {
        unsigned int f  = c * 116 + j;              // f = ic*9 + dy*3 + dx
        unsigned int ic = (f * 7282u) >> 16;        // f/9  (f<576)
        unsigned int r9 = f - ic * 9;
        unsigned int dy = (r9 * 11u) >> 5;          // r9/3
        unsigned int dx = r9 - dy * 3;
        int iy = y + (int)dy - 1, ix = x + (int)dx - 1;
        if (iy >= 0 && iy < 32 && ix >= 0 && ix < 32)
          bv = quant_in(in[((b * 64 + ic) * 32 + iy) * 32 + ix]);
      }
      pack |= bv << (8 * i);
    }
    ((unsigned int*)Aq)[widx] = pack;
  } else {
    // ---- weight pipeline: 9 blocks. Each computes the global |w| max
    // (fmax is order-insensitive -> identical result), then quantizes 1/9 of
    // the weights into the swizzled packed byte matrix. ----
    int q = bid - 2560;                             // 0..8
    float a = 0.0f;
    #pragma unroll 4
    for (int i = 0; i < 36; ++i) {                  // 9216 float4 = all weights
      float4 v = ((const float4*)w)[i * 256 + tid];
      a = fmaxf(a, fmaxf(fmaxf(fabsf(v.x), fabsf(v.y)),
                         fmaxf(fabsf(v.z), fabsf(v.w))));
    }
    #pragma unroll
    for (int off = 32; off > 0; off >>= 1)
      a = fmaxf(a, __shfl_down(a, off, 64));
    if ((tid & 63) == 0) smax[tid >> 6] = a;
    __syncthreads();
    float norm = fmaxf(fmaxf(smax[0], smax[1]), fmaxf(smax[2], smax[3]));
    norm = (norm > 0.0f) ? norm : 1.0f;
    if (q == 0 && tid == 0) nrm[0] = norm;
    float sc = 255.0f / norm;

    // phase 2: quantize 4 float4-groups per thread (4-groups never straddle an
    // oc row (576%4==0) or a 116-chunk (116%4==0) -> one dword per sign each)
    #pragma unroll
    for (int g = 0; g < 4; ++g) {
      int grp = (q * 4 + g) * 256 + tid;            // [0, 9216) float4 groups
      unsigned int gf = (unsigned)grp * 4u;         // global weight index
      unsigned int oc = gf / 576u;
      unsigned int f  = gf - oc * 576u;
      unsigned int c  = f / 116u;
      unsigned int j  = f - c * 116u;
      unsigned int base = (oc >> 4) * B_SLICE + (oc & 15) * 640 + c * 128 + j;
      unsigned int key  = (oc & 7) << 4;            // XOR swizzle (matches read)
      float4 wv = ((const float4*)w)[grp];
      int p0 = (int)rintf(fmaxf(wv.x, 0.0f) * sc);
      int p1 = (int)rintf(fmaxf(wv.y, 0.0f) * sc);
      int p2 = (int)rintf(fmaxf(wv.z, 0.0f) * sc);
      int p3 = (int)rintf(fmaxf(wv.w, 0.0f) * sc);
      int n0 = (int)rintf(fmaxf(-wv.x, 0.0f) * sc);
      int n1 = (int)rintf(fmaxf(-wv.y, 0.0f) * sc);
      int n2 = (int)rintf(fmaxf(-wv.z, 0.0f) * sc);
      int n3 = (int)rintf(fmaxf(-wv.w, 0.0f) * sc);
      unsigned int Pp = (unsigned)p0 | ((unsigned)p1 << 8) |
                        ((unsigned)p2 << 16) | ((unsigned)p3 << 24);
      unsigned int Pn = (unsigned)n0 | ((unsigned)n1 << 8) |
                        ((unsigned)n2 << 16) | ((unsigned)n3 << 24);
      *(unsigned int*)(Bqb + (base ^ key))          = Pp;
      *(unsigned int*)(Bqb + ((base + B_SG) ^ key)) = Pn;
    }

    // phase 3: zero the chunk-pad dwords (2048 total; ws is poisoned each iter)
    // per (slice,sg,row): chunks 0-3 pad dwords {29,30,31}, chunk 4 {28..31}
    int tg = q * 256 + tid;                         // [0, 2304)
    if (tg < 2048) {
      int slice = tg >> 9;                          // 512 pad dwords per otile
      int r  = tg & 511;
      int sg = r >> 8;
      int rr = r & 255;
      int row = rr >> 4, s = rr & 15;
      int c, d;
      if (s < 12) { c = s / 3; d = 29 + s - 3 * c; }
      else        { c = 4;     d = 16 + s; }        // 28..31
      unsigned int base = slice * B_SLICE + sg * B_SG + row * 640 + c * 128 + d * 4;
      *(unsigned int*)(Bqb + (base ^ (((unsigned)row & 7) << 4))) = 0u;
    }
  }
}

// extract 2-bit field s of each byte in a packed dword vector
__device__ __forceinline__ v4i bits2(v4u w, int s) {
  v4u r = (w >> (unsigned)(2 * s)) & 0x03030303u;
  return (v4i)r;
}

// ---------------------------------------------------------------------------
// k_main: stage 20KB B slice -> LDS, then pure MFMA/clip/fold.
// grid: 256 blocks (64 mtiles x 4 otiles), 256 thr = 4 waves (16m x 16o each)
// ---------------------------------------------------------------------------
__global__ __launch_bounds__(256) void k_main(
    const unsigned char* __restrict__ Aq, const unsigned char* __restrict__ Bqb,
    const float* __restrict__ nrm, float* __restrict__ out)
{
  __shared__ __align__(16) unsigned char Bl[B_SLICE];

  int tid   = threadIdx.x;
  int lane  = tid & 63;
  int wave  = tid >> 6;
  int mtile = blockIdx.x >> 2;
  int otile = blockIdx.x & 3;

  // ---- stage this otile's swizzled B slice (coalesced, conflict-free) ----
  const unsigned char* src = Bqb + otile * B_SLICE;
  #pragma unroll
  for (int i = 0; i < 5; ++i)
    *(v4u*)(Bl + i * 4096 + tid * 16) = *(const v4u*)(src + i * 4096 + tid * 16);
  __syncthreads();

  // ---- MFMA main loop ----
  int r16  = lane & 15;
  int kgrp = lane >> 4;                 // A: m=lane&15,k=kgrp*16+j ; B: n=lane&15
  int m = mtile * 64 + wave * 16 + r16;
  const unsigned char* ap = Aq + m * 640 + kgrp * 16;
  unsigned int key = ((unsigned)r16 & 7) << 4;
  unsigned int b0o = ((unsigned)(r16 * 640 + kgrp * 16)) ^ key;       // pos, lo
  unsigned int b1o = ((unsigned)(r16 * 640 + kgrp * 16 + 64)) ^ key;  // pos, hi
  float fsc = nrm[0] / 255.0f;

  v4i outacc = {0, 0, 0, 0};

  #pragma unroll
  for (int c = 0; c < 5; ++c) {
    v4u a0 = *(const v4u*)(ap + c * 128);
    v4u a1 = *(const v4u*)(ap + c * 128 + 64);
    v4u p0 = *(const v4u*)(Bl + b0o + c * 128);
    v4u p1 = *(const v4u*)(Bl + b1o + c * 128);
    v4u n0 = *(const v4u*)(Bl + b0o + B_SG + c * 128);
    v4u n1 = *(const v4u*)(Bl + b1o + B_SG + c * 128);

    v4i btp0[4], btp1[4], btn0[4], btn1[4];
    #pragma unroll
    for (int t = 0; t < 4; ++t) {
      btp0[t] = bits2(p0, t); btp1[t] = bits2(p1, t);
      btn0[t] = bits2(n0, t); btn1[t] = bits2(n1, t);
    }

    #pragma unroll
    for (int s = 0; s < 4; ++s) {
      v4i as0 = bits2(a0, s), as1 = bits2(a1, s);
      #pragma unroll
      for (int t = 0; t < 4; ++t) {
        v4i z = {0, 0, 0, 0};
        v4i pacc = __builtin_amdgcn_mfma_i32_16x16x64_i8(as0, btp0[t], z, 0, 0, 0);
        pacc     = __builtin_amdgcn_mfma_i32_16x16x64_i8(as1, btp1[t], pacc, 0, 0, 0);
        v4i nacc = __builtin_amdgcn_mfma_i32_16x16x64_i8(as0, btn0[t], z, 0, 0, 0);
        nacc     = __builtin_amdgcn_mfma_i32_16x16x64_i8(as1, btn1[t], nacc, 0, 0, 0);
        int sh = 2 * (s + t);
        #pragma unroll
        for (int r = 0; r < 4; ++r) {
          int d = (pacc[r] < 31 ? pacc[r] : 31) - (nacc[r] < 31 ? nacc[r] : 31);
          outacc[r] += d << sh;   // |outacc| <= 31*85*85*5 ~ 1.12e6, exact
        }
      }
    }
  }

  // C/D layout: col(n=o) = lane&15, row(m) = (lane>>4)*4 + r
  int oc = otile * 16 + r16;
  #pragma unroll
  for (int r = 0; r < 4; ++r) {
    int mo = mtile * 64 + wave * 16 + kgrp * 4 + r;
    int b = mo >> 10, p = mo & 1023;
    out[(b * 64 + oc) * 1024 + p] = (float)outacc[r] * fsc;
  }
}

extern "C" void kernel_launch(void* const* d_in, const int* in_sizes, int n_in,
                              void* d_out, int out_size, void* d_ws, size_t ws_size,
                              hipStream_t stream) {
  const float* inp = (const float*)d_in[0];   // (4,64,32,32) f32
  const float* wgt = (const float*)d_in[1];   // (64,64,3,3)  f32
  float* out = (float*)d_out;                 // 262144 + 1 f32
  unsigned char* ws = (unsigned char*)d_ws;

  float*         nrm = (float*)(ws + WS_NORM);
  unsigned char* Bqb = ws + WS_B;
  unsigned char* Aq  = ws + WS_AQ;

  k_prep<<<2569, 256, 0, stream>>>(inp, wgt, Aq, Bqb, nrm, out + 262144);
  k_main<<<256, 256, 0, stream>>>(Aq, Bqb, nrm, out);
}